// Round 7
// baseline (231.098 us; speedup 1.0000x reference)
//
#include <hip/hip_runtime.h>
#include <stdint.h>

#define D 128

typedef __bf16 bf16x8 __attribute__((ext_vector_type(8)));
typedef float f32x4 __attribute__((ext_vector_type(4)));

__device__ inline float bf2f(unsigned short u) {
    return __uint_as_float((unsigned)u << 16);
}
__device__ inline unsigned short f2bf(float f) {
    unsigned u = __float_as_uint(f);
    return (unsigned short)((u + 0x7FFF + ((u >> 16) & 1)) >> 16);  // RNE
}

// ---------------- prep: blocks 0,1 transpose W1/W2 -> bf16 n-major; rest zero pk ----------------
__global__ __launch_bounds__(256) void k_prep(const float* __restrict__ W1,
                                              unsigned short* __restrict__ Wt1,
                                              const float* __restrict__ W2,
                                              unsigned short* __restrict__ Wt2,
                                              unsigned long long* __restrict__ pk, int n) {
    __shared__ float t[128 * 132];
    const int tid = threadIdx.x;
    if (blockIdx.x < 2) {
        const float* W = (blockIdx.x == 0) ? W1 : W2;
        unsigned short* Wt = (blockIdx.x == 0) ? Wt1 : Wt2;
        for (int i = tid; i < 128 * 32; i += 256) {
            int r = i >> 5, c = i & 31;
            float4 v = *(const float4*)(W + r * 128 + c * 4);
            float* dp = &t[r * 132 + c * 4];
            dp[0] = v.x; dp[1] = v.y; dp[2] = v.z; dp[3] = v.w;
        }
        __syncthreads();
        for (int i = tid; i < 128 * 32; i += 256) {
            int nn = i >> 5, c = i & 31;
            ushort4 o;
            o.x = f2bf(t[(c * 4 + 0) * 132 + nn]);
            o.y = f2bf(t[(c * 4 + 1) * 132 + nn]);
            o.z = f2bf(t[(c * 4 + 2) * 132 + nn]);
            o.w = f2bf(t[(c * 4 + 3) * 132 + nn]);
            *(ushort4*)(Wt + nn * 128 + c * 4) = o;
        }
    } else {
        int i = (blockIdx.x - 2) * 256 + tid;
        if (i < n) pk[i] = 0ULL;
    }
}

// ---------------- MFMA GEMM body: H(bf16) = X @ Wt^T over one 64-row tile ----------------
// No LDS staging: A-frags straight from X rows, B-frags straight from Wt (L2-broadcast).
// LDS only for the C-repack epilogue (sE: 64x136 shorts).
template <bool IN_BF16>
__device__ inline void mfma_body(unsigned short* sE,
                                 const void* __restrict__ Xv,
                                 const unsigned short* __restrict__ Wt,
                                 unsigned short* __restrict__ H, int n, int blk) {
    const int tid = threadIdx.x;
    const int row0 = blk * 64;
    const int lane = tid & 63;
    const int wv = tid >> 6;
    const int qm = lane & 15;
    const int quad = lane >> 4;

    const int arow = row0 + wv * 16 + qm;
    const int ar = (arow < n) ? arow : (n - 1);   // clamp for safe load; masked at store

    f32x4 acc[8];
#pragma unroll
    for (int i = 0; i < 8; ++i) acc[i] = (f32x4){0.f, 0.f, 0.f, 0.f};

#pragma unroll
    for (int kb = 0; kb < 4; ++kb) {
        const int koff = kb * 32 + quad * 8;
        bf16x8 a;
        if (IN_BF16) {
            a = *(const bf16x8*)((const unsigned short*)Xv + (size_t)ar * 128 + koff);
        } else {
            const float* Xf = (const float*)Xv + (size_t)ar * 128 + koff;
            float4 v0 = *(const float4*)(Xf);
            float4 v1 = *(const float4*)(Xf + 4);
            union { bf16x8 v; ushort4 u[2]; } cv;
            cv.u[0].x = f2bf(v0.x); cv.u[0].y = f2bf(v0.y);
            cv.u[0].z = f2bf(v0.z); cv.u[0].w = f2bf(v0.w);
            cv.u[1].x = f2bf(v1.x); cv.u[1].y = f2bf(v1.y);
            cv.u[1].z = f2bf(v1.z); cv.u[1].w = f2bf(v1.w);
            a = cv.v;
        }
#pragma unroll
        for (int n0 = 0; n0 < 8; ++n0) {
            bf16x8 b = *(const bf16x8*)(Wt + (n0 * 16 + qm) * 128 + koff);
            acc[n0] = __builtin_amdgcn_mfma_f32_16x16x32_bf16(a, b, acc[n0], 0, 0, 0);
        }
    }

    // epilogue: repack C through LDS for coalesced 16B stores
#pragma unroll
    for (int n0 = 0; n0 < 8; ++n0)
#pragma unroll
        for (int r = 0; r < 4; ++r)
            sE[(wv * 16 + quad * 4 + r) * 136 + n0 * 16 + qm] = f2bf(acc[n0][r]);
    __syncthreads();

    const int row_in = lane >> 2;
    const int c0 = (lane & 3) * 4;
    const int grow = row0 + wv * 16 + row_in;
    if (grow < n) {
#pragma unroll
        for (int j = 0; j < 4; ++j)
            *(int4*)(H + (size_t)grow * 128 + (c0 + j) * 8) =
                *(const int4*)(&sE[(wv * 16 + row_in) * 136 + (c0 + j) * 8]);
    }
}

// ---------------- FUSED: blocks [0,gb) mfma layer-1 (f32 in); rest: edge count, 4 edges/thread ----------------
__global__ __launch_bounds__(256, 4) void k_cm(const float* __restrict__ X,
                                               const unsigned short* __restrict__ Wt,
                                               unsigned short* __restrict__ H, int n, int gb,
                                               const int* __restrict__ ei,
                                               const float* __restrict__ ew,
                                               unsigned long long* __restrict__ pk,
                                               int* __restrict__ rank, int E) {
    __shared__ unsigned short sE[64 * 136];
    if (blockIdx.x < gb) {
        mfma_body<false>(sE, (const void*)X, Wt, H, n, blockIdx.x);
    } else {
        const int base = (blockIdx.x - gb) * 1024 + threadIdx.x;
        int d[4]; float w[4];
        bool ok[4];
#pragma unroll
        for (int k = 0; k < 4; ++k) {
            int e = base + k * 256;
            ok[k] = (e < E);
            d[k] = ok[k] ? ei[E + e] : 0;
            w[k] = ok[k] ? ew[e] : 0.f;
        }
#pragma unroll
        for (int k = 0; k < 4; ++k) {
            if (ok[k]) {
                unsigned int fx = (unsigned int)(w[k] * 16777216.0f);
                unsigned long long old =
                    atomicAdd(&pk[d[k]], (1ULL << 32) | (unsigned long long)fx);
                rank[base + k * 256] = (int)(old >> 32);
            }
        }
    }
}

// standalone mfma for layer 2 (bf16 in)
__global__ __launch_bounds__(256, 4) void k_mfma2(const unsigned short* __restrict__ X,
                                                  const unsigned short* __restrict__ Wt,
                                                  unsigned short* __restrict__ H, int n) {
    __shared__ unsigned short sE[64 * 136];
    mfma_body<true>(sE, (const void*)X, Wt, H, n, blockIdx.x);
}

// ---------------- scanA: per-block exclusive scan of counts + block sums ----------------
__global__ __launch_bounds__(256) void k_scanA(const unsigned long long* __restrict__ pk,
                                               int* rowstart, int* bsums, int n) {
    __shared__ int tmp[256];
    int tid = threadIdx.x;
    int i = blockIdx.x * 256 + tid;
    int v = (i < n) ? (int)(pk[i] >> 32) : 0;
    tmp[tid] = v;
    __syncthreads();
    for (int off = 1; off < 256; off <<= 1) {
        int t = (tid >= off) ? tmp[tid - off] : 0;
        __syncthreads();
        tmp[tid] += t;
        __syncthreads();
    }
    if (i < n) rowstart[i] = tmp[tid] - v;
    if (tid == 255) bsums[blockIdx.x] = tmp[255];
}

// ---------------- scanBC: each block sums bsums[0..b-1]; finalize rowstart/cnt/dinv ----------------
__global__ __launch_bounds__(256) void k_scanBC(int* rowstart, const int* __restrict__ bsums,
                                                const unsigned long long* __restrict__ pk,
                                                int* cnt, float* dinv, int n) {
    __shared__ int sred[4];
    int tid = threadIdx.x;
    int v = (tid < (int)blockIdx.x) ? bsums[tid] : 0;   // grid = nb <= 256
#pragma unroll
    for (int off = 32; off; off >>= 1) v += __shfl_down(v, off);
    if ((tid & 63) == 0) sred[tid >> 6] = v;
    __syncthreads();
    int total = sred[0] + sred[1] + sred[2] + sred[3];
    int i = blockIdx.x * 256 + tid;
    if (i < n) {
        rowstart[i] += total;
        unsigned long long pv = pk[i];
        cnt[i] = (int)(pv >> 32);
        float deg = 1.0f + (float)(unsigned int)(pv & 0xFFFFFFFFu) * (1.0f / 16777216.0f);
        dinv[i] = rsqrtf(deg);
    }
}

// ---------------- edges: place packed (src, nrm) records; no atomics; 2 edges/thread ----------------
__global__ __launch_bounds__(256) void k_edges(const int* __restrict__ ei,
                                               const float* __restrict__ ew,
                                               const float* __restrict__ dinv,
                                               const int* __restrict__ rowstart,
                                               const int* __restrict__ rank,
                                               int2* __restrict__ erec, int E) {
    const int base = blockIdx.x * 512 + threadIdx.x;
#pragma unroll
    for (int k = 0; k < 2; ++k) {
        int e = base + k * 256;
        if (e < E) {
            int s = ei[e];
            int d = ei[E + e];
            int p = rowstart[d] + rank[e];
            float nm = dinv[s] * ew[e] * dinv[d];
            erec[p] = make_int2(s, __float_as_int(nm));
        }
    }
}

// ---------------- gather: OUT[d] = b + dinv[d]^2*H[d] + sum nrm*H[src] ----------------
template <bool OUT_BF16>
__global__ __launch_bounds__(256) void k_gather(const ushort4* __restrict__ H4,
                                                const int2* __restrict__ erec,
                                                const int* __restrict__ rowstart,
                                                const int* __restrict__ cnt,
                                                const float* __restrict__ dinv,
                                                const float4* __restrict__ bias4,
                                                void* __restrict__ OUTv, int n) {
    const int lane = threadIdx.x & 31;
    const int node = blockIdx.x * 8 + (threadIdx.x >> 5);
    if (node >= n) return;
    const int start = rowstart[node];
    const int m = cnt[node];
    const float di = dinv[node];
    const float dii = di * di;

    float4 b = bias4[lane];
    ushort4 h = H4[(size_t)node * 32 + lane];
    float ax = b.x + dii * bf2f(h.x);
    float ay = b.y + dii * bf2f(h.y);
    float az = b.z + dii * bf2f(h.z);
    float aw = b.w + dii * bf2f(h.w);

    int j = 0;
    for (; j + 4 <= m; j += 4) {
        const int base = start + j;
        int2 e0 = erec[base + 0], e1 = erec[base + 1];
        int2 e2 = erec[base + 2], e3 = erec[base + 3];
        float w0 = __int_as_float(e0.y), w1 = __int_as_float(e1.y);
        float w2 = __int_as_float(e2.y), w3 = __int_as_float(e3.y);
        ushort4 v0 = H4[(size_t)e0.x * 32 + lane];
        ushort4 v1 = H4[(size_t)e1.x * 32 + lane];
        ushort4 v2 = H4[(size_t)e2.x * 32 + lane];
        ushort4 v3 = H4[(size_t)e3.x * 32 + lane];
        ax += w0 * bf2f(v0.x); ay += w0 * bf2f(v0.y); az += w0 * bf2f(v0.z); aw += w0 * bf2f(v0.w);
        ax += w1 * bf2f(v1.x); ay += w1 * bf2f(v1.y); az += w1 * bf2f(v1.z); aw += w1 * bf2f(v1.w);
        ax += w2 * bf2f(v2.x); ay += w2 * bf2f(v2.y); az += w2 * bf2f(v2.z); aw += w2 * bf2f(v2.w);
        ax += w3 * bf2f(v3.x); ay += w3 * bf2f(v3.y); az += w3 * bf2f(v3.z); aw += w3 * bf2f(v3.w);
    }
    for (; j < m; ++j) {
        int2 er = erec[start + j];
        float w = __int_as_float(er.y);
        ushort4 v = H4[(size_t)er.x * 32 + lane];
        ax += w * bf2f(v.x); ay += w * bf2f(v.y); az += w * bf2f(v.z); aw += w * bf2f(v.w);
    }
    if (OUT_BF16) {
        ushort4 o;
        o.x = f2bf(fmaxf(ax, 0.f)); o.y = f2bf(fmaxf(ay, 0.f));
        o.z = f2bf(fmaxf(az, 0.f)); o.w = f2bf(fmaxf(aw, 0.f));
        ((ushort4*)OUTv)[(size_t)node * 32 + lane] = o;
    } else {
        float4 o; o.x = ax; o.y = ay; o.z = az; o.w = aw;
        ((float4*)OUTv)[(size_t)node * 32 + lane] = o;
    }
}

extern "C" void kernel_launch(void* const* d_in, const int* in_sizes, int n_in,
                              void* d_out, int out_size, void* d_ws, size_t ws_size,
                              hipStream_t stream) {
    const float* x  = (const float*)d_in[0];
    const int*   ei = (const int*)d_in[1];    // [2,E] int32
    const float* ew = (const float*)d_in[2];
    const float* W1 = (const float*)d_in[3];
    const float* b1 = (const float*)d_in[4];
    const float* W2 = (const float*)d_in[5];
    const float* b2 = (const float*)d_in[6];
    float* out = (float*)d_out;

    const int N = in_sizes[0] / D;
    const int E = in_sizes[2];

    char* p = (char*)d_ws;
    auto alloc = [&](size_t bytes) {
        void* r = (void*)p;
        p += (bytes + 255) & ~(size_t)255;
        return r;
    };
    unsigned long long* pk = (unsigned long long*)alloc((size_t)N * 8);
    float* dinv     = (float*)alloc((size_t)N * 4);
    int*   cnt      = (int*)alloc((size_t)N * 4);
    int*   rowstart = (int*)alloc((size_t)N * 4);
    int*   bsums    = (int*)alloc(1024 * 4);
    int*   rank     = (int*)alloc((size_t)E * 4);
    int2*  erec     = (int2*)alloc((size_t)E * 8);
    unsigned short* B1  = (unsigned short*)alloc((size_t)N * D * 2);  // H bf16
    unsigned short* B2h = (unsigned short*)alloc((size_t)N * D * 2);  // relu(agg1) bf16
    unsigned short* Wt1 = (unsigned short*)alloc(128 * 128 * 2);
    unsigned short* Wt2 = (unsigned short*)alloc(128 * 128 * 2);

    const int nb  = (N + 255) / 256;
    const int eb2 = (E + 511) / 512;
    const int eb4 = (E + 1023) / 1024;
    const int gb  = (N + 63) / 64;
    const int hb  = (N + 7) / 8;

    // 1. prep: W transposes + pk zero
    k_prep<<<2 + nb, 256, 0, stream>>>(W1, Wt1, W2, Wt2, pk, N);
    // 2. fused: mfma layer-1 || edge count (4 edges/thread)
    k_cm<<<gb + eb4, 256, 0, stream>>>(x, Wt1, B1, N, gb, ei, ew, pk, rank, E);
    // 3-4. scan
    k_scanA<<<nb, 256, 0, stream>>>(pk, rowstart, bsums, N);
    k_scanBC<<<nb, 256, 0, stream>>>(rowstart, bsums, pk, cnt, dinv, N);
    // 5. CSR fill
    k_edges<<<eb2, 256, 0, stream>>>(ei, ew, dinv, rowstart, rank, erec, E);
    // 6. gather layer-1 -> relu -> bf16
    k_gather<true><<<hb, 256, 0, stream>>>((const ushort4*)B1, erec, rowstart, cnt,
                                           dinv, (const float4*)b1, (void*)B2h, N);
    // 7. mfma layer-2
    k_mfma2<<<gb, 256, 0, stream>>>(B2h, Wt2, B1, N);
    // 8. gather layer-2 -> f32 out
    k_gather<false><<<hb, 256, 0, stream>>>((const ushort4*)B1, erec, rowstart, cnt,
                                            dinv, (const float4*)b2, (void*)out, N);
}

// Round 8
// 220.890 us; speedup vs baseline: 1.0462x; 1.0462x over previous
//
#include <hip/hip_runtime.h>
#include <stdint.h>

#define D 128
#define EPB 4096   // edges per histogram/scatter block
#define CSZ 128    // nodes per cluster (cluster = dst >> 7)

typedef __bf16 bf16x8 __attribute__((ext_vector_type(8)));
typedef float f32x4 __attribute__((ext_vector_type(4)));

__device__ inline float bf2f(unsigned short u) {
    return __uint_as_float((unsigned)u << 16);
}
__device__ inline unsigned short f2bf(float f) {
    unsigned u = __float_as_uint(f);
    return (unsigned short)((u + 0x7FFF + ((u >> 16) & 1)) >> 16);  // RNE
}

// ---------------- prep: transpose W1/W2 -> bf16 n-major ----------------
__global__ __launch_bounds__(256) void k_prep(const float* __restrict__ W1,
                                              unsigned short* __restrict__ Wt1,
                                              const float* __restrict__ W2,
                                              unsigned short* __restrict__ Wt2) {
    __shared__ float t[128 * 132];
    const int tid = threadIdx.x;
    const float* W = (blockIdx.x == 0) ? W1 : W2;
    unsigned short* Wt = (blockIdx.x == 0) ? Wt1 : Wt2;
    for (int i = tid; i < 128 * 32; i += 256) {
        int r = i >> 5, c = i & 31;
        float4 v = *(const float4*)(W + r * 128 + c * 4);
        float* dp = &t[r * 132 + c * 4];
        dp[0] = v.x; dp[1] = v.y; dp[2] = v.z; dp[3] = v.w;
    }
    __syncthreads();
    for (int i = tid; i < 128 * 32; i += 256) {
        int nn = i >> 5, c = i & 31;
        ushort4 o;
        o.x = f2bf(t[(c * 4 + 0) * 132 + nn]);
        o.y = f2bf(t[(c * 4 + 1) * 132 + nn]);
        o.z = f2bf(t[(c * 4 + 2) * 132 + nn]);
        o.w = f2bf(t[(c * 4 + 3) * 132 + nn]);
        *(ushort4*)(Wt + nn * 128 + c * 4) = o;
    }
}

// ---------------- MFMA GEMM body (R6-verified): direct-global A/B frags ----------------
template <bool IN_BF16>
__device__ inline void mfma_body(unsigned short* sE,
                                 const void* __restrict__ Xv,
                                 const unsigned short* __restrict__ Wt,
                                 unsigned short* __restrict__ H, int n, int blk) {
    const int tid = threadIdx.x;
    const int row0 = blk * 64;
    const int lane = tid & 63;
    const int wv = tid >> 6;
    const int qm = lane & 15;
    const int quad = lane >> 4;

    const int arow = row0 + wv * 16 + qm;
    const int ar = (arow < n) ? arow : (n - 1);

    f32x4 acc[8];
#pragma unroll
    for (int i = 0; i < 8; ++i) acc[i] = (f32x4){0.f, 0.f, 0.f, 0.f};

#pragma unroll
    for (int kb = 0; kb < 4; ++kb) {
        const int koff = kb * 32 + quad * 8;
        bf16x8 a;
        if (IN_BF16) {
            a = *(const bf16x8*)((const unsigned short*)Xv + (size_t)ar * 128 + koff);
        } else {
            const float* Xf = (const float*)Xv + (size_t)ar * 128 + koff;
            float4 v0 = *(const float4*)(Xf);
            float4 v1 = *(const float4*)(Xf + 4);
            union { bf16x8 v; ushort4 u[2]; } cv;
            cv.u[0].x = f2bf(v0.x); cv.u[0].y = f2bf(v0.y);
            cv.u[0].z = f2bf(v0.z); cv.u[0].w = f2bf(v0.w);
            cv.u[1].x = f2bf(v1.x); cv.u[1].y = f2bf(v1.y);
            cv.u[1].z = f2bf(v1.z); cv.u[1].w = f2bf(v1.w);
            a = cv.v;
        }
#pragma unroll
        for (int n0 = 0; n0 < 8; ++n0) {
            bf16x8 b = *(const bf16x8*)(Wt + (n0 * 16 + qm) * 128 + koff);
            acc[n0] = __builtin_amdgcn_mfma_f32_16x16x32_bf16(a, b, acc[n0], 0, 0, 0);
        }
    }

#pragma unroll
    for (int n0 = 0; n0 < 8; ++n0)
#pragma unroll
        for (int r = 0; r < 4; ++r)
            sE[(wv * 16 + quad * 4 + r) * 136 + n0 * 16 + qm] = f2bf(acc[n0][r]);
    __syncthreads();

    const int row_in = lane >> 2;
    const int c0 = (lane & 3) * 4;
    const int grow = row0 + wv * 16 + row_in;
    if (grow < n) {
#pragma unroll
        for (int j = 0; j < 4; ++j)
            *(int4*)(H + (size_t)grow * 128 + (c0 + j) * 8) =
                *(const int4*)(&sE[(wv * 16 + row_in) * 136 + (c0 + j) * 8]);
    }
}

// ---------------- FUSED: blocks [0,gb) mfma layer-1; rest: cluster histogram (LDS atomics) ----------------
__global__ __launch_bounds__(256, 4) void k_histmfma(const float* __restrict__ X,
                                                     const unsigned short* __restrict__ Wt,
                                                     unsigned short* __restrict__ H, int n, int gb,
                                                     const int* __restrict__ ei,
                                                     unsigned int* __restrict__ bh,
                                                     int E, int C) {
    __shared__ char arena[64 * 136 * 2];
    if (blockIdx.x < gb) {
        mfma_body<false>((unsigned short*)arena, (const void*)X, Wt, H, n, blockIdx.x);
    } else {
        unsigned int* hist = (unsigned int*)arena;  // C counters
        const int b = blockIdx.x - gb;
        for (int i = threadIdx.x; i < C; i += 256) hist[i] = 0;
        __syncthreads();
        const int base = b * EPB + threadIdx.x;
#pragma unroll
        for (int k = 0; k < EPB / 256; ++k) {
            int e = base + k * 256;
            if (e < E) atomicAdd(&hist[((unsigned)ei[E + e]) >> 7], 1u);
        }
        __syncthreads();
        for (int i = threadIdx.x; i < C; i += 256)
            bh[(size_t)b * C + i] = hist[i];  // coalesced; scan reads strided
    }
}

// ---------------- scanA2: exclusive scan (cluster-major order) of bh ----------------
__global__ __launch_bounds__(256) void k_scanA2(const unsigned int* __restrict__ bh,
                                                int* __restrict__ ebase, int* __restrict__ bsums,
                                                int total, int C, int B1) {
    __shared__ int tmp[256];
    const int tid = threadIdx.x;
    const int i = blockIdx.x * 256 + tid;
    int v = 0;
    if (i < total) {
        int c = i / B1;
        int b = i - c * B1;
        v = (int)bh[(size_t)b * C + c];
    }
    tmp[tid] = v;
    __syncthreads();
    for (int off = 1; off < 256; off <<= 1) {
        int t = (tid >= off) ? tmp[tid - off] : 0;
        __syncthreads();
        tmp[tid] += t;
        __syncthreads();
    }
    if (i < total) ebase[i] = tmp[tid] - v;
    if (tid == 255) bsums[blockIdx.x] = tmp[255];
}

// ---------------- scanB2: add per-block offsets (grid <= 256) ----------------
__global__ __launch_bounds__(256) void k_scanB2(int* __restrict__ ebase,
                                                const int* __restrict__ bsums, int total) {
    __shared__ int sred[4];
    const int tid = threadIdx.x;
    int v = (tid < (int)blockIdx.x) ? bsums[tid] : 0;
#pragma unroll
    for (int off = 32; off; off >>= 1) v += __shfl_down(v, off);
    if ((tid & 63) == 0) sred[tid >> 6] = v;
    __syncthreads();
    int tot = sred[0] + sred[1] + sred[2] + sred[3];
    int i = blockIdx.x * 256 + tid;
    if (i < total) ebase[i] += tot;
}

// ---------------- scat: bucket edges by cluster; rank via LDS returning atomic ----------------
__global__ __launch_bounds__(256) void k_scat(const int* __restrict__ ei,
                                              const float* __restrict__ ew,
                                              const int* __restrict__ ebase,
                                              int2* __restrict__ brec, int E, int C, int B1) {
    __shared__ unsigned int cur[512];
    const int b = blockIdx.x;
    for (int i = threadIdx.x; i < C; i += 256) cur[i] = 0;
    __syncthreads();
    const int base = b * EPB + threadIdx.x;
#pragma unroll
    for (int k = 0; k < EPB / 256; ++k) {
        int e = base + k * 256;
        if (e < E) {
            int s = ei[e];
            unsigned d = (unsigned)ei[E + e];
            float w = ew[e];
            int c = d >> 7;
            unsigned r = atomicAdd(&cur[c], 1u);
            int pos = ebase[c * B1 + b] + (int)r;
            brec[pos] = make_int2((int)((d << 16) | (unsigned)s), __float_as_int(w));
        }
    }
}

// ---------------- cbuild: per-cluster CSR finalize (all LDS atomics) ----------------
__global__ __launch_bounds__(256) void k_cbuild(const int2* __restrict__ brec,
                                                const int* __restrict__ ebase,
                                                int2* __restrict__ erec,
                                                int* __restrict__ rowstart,
                                                int* __restrict__ cnt,
                                                float* __restrict__ dinv,
                                                int n, int C, int B1, int E) {
    __shared__ unsigned int hcnt[CSZ], hdeg[CSZ], lsc[CSZ], curs[CSZ];
    const int c = blockIdx.x;
    const int tid = threadIdx.x;
    const int cs = ebase[c * B1];
    const int ce = (c + 1 < C) ? ebase[(c + 1) * B1] : E;
    if (tid < CSZ) { hcnt[tid] = 0; hdeg[tid] = 0; }
    __syncthreads();
    for (int i = cs + tid; i < ce; i += 256) {
        int2 r = brec[i];
        int local = (int)(((unsigned)r.x) >> 16) & (CSZ - 1);
        atomicAdd(&hcnt[local], 1u);
        atomicAdd(&hdeg[local], (unsigned)(__int_as_float(r.y) * 16777216.0f));
    }
    __syncthreads();
    if (tid < CSZ) lsc[tid] = hcnt[tid];
    __syncthreads();
    for (int off = 1; off < CSZ; off <<= 1) {
        unsigned t = (tid < CSZ && tid >= off) ? lsc[tid - off] : 0u;
        __syncthreads();
        if (tid < CSZ) lsc[tid] += t;
        __syncthreads();
    }
    if (tid < CSZ) {
        unsigned excl = lsc[tid] - hcnt[tid];
        curs[tid] = excl;
        int node = c * CSZ + tid;
        if (node < n) {
            rowstart[node] = cs + (int)excl;
            cnt[node] = (int)hcnt[tid];
            float deg = 1.0f + (float)hdeg[tid] * (1.0f / 16777216.0f);
            dinv[node] = rsqrtf(deg);
        }
    }
    __syncthreads();
    for (int i = cs + tid; i < ce; i += 256) {
        int2 r = brec[i];
        int local = (int)(((unsigned)r.x) >> 16) & (CSZ - 1);
        unsigned rk = atomicAdd(&curs[local], 1u);
        erec[cs + (int)rk] = r;
    }
}

// ---------------- nrm: (dst<<16|src, ew) -> (src, norm) in place ----------------
__global__ __launch_bounds__(256) void k_nrm(int2* __restrict__ erec,
                                             const float* __restrict__ dinv, int E) {
    const int base = blockIdx.x * 512 + threadIdx.x;
#pragma unroll
    for (int k = 0; k < 2; ++k) {
        int e = base + k * 256;
        if (e < E) {
            int2 r = erec[e];
            unsigned dst = ((unsigned)r.x) >> 16;
            int src = r.x & 0xFFFF;
            float nm = dinv[src] * __int_as_float(r.y) * dinv[dst];
            erec[e] = make_int2(src, __float_as_int(nm));
        }
    }
}

// standalone mfma for layer 2 (bf16 in)
__global__ __launch_bounds__(256, 4) void k_mfma2(const unsigned short* __restrict__ X,
                                                  const unsigned short* __restrict__ Wt,
                                                  unsigned short* __restrict__ H, int n) {
    __shared__ unsigned short sE[64 * 136];
    mfma_body<true>(sE, (const void*)X, Wt, H, n, blockIdx.x);
}

// ---------------- gather: OUT[d] = b + dinv[d]^2*H[d] + sum nrm*H[src] ----------------
template <bool OUT_BF16>
__global__ __launch_bounds__(256) void k_gather(const ushort4* __restrict__ H4,
                                                const int2* __restrict__ erec,
                                                const int* __restrict__ rowstart,
                                                const int* __restrict__ cnt,
                                                const float* __restrict__ dinv,
                                                const float4* __restrict__ bias4,
                                                void* __restrict__ OUTv, int n) {
    const int lane = threadIdx.x & 31;
    const int node = blockIdx.x * 8 + (threadIdx.x >> 5);
    if (node >= n) return;
    const int start = rowstart[node];
    const int m = cnt[node];
    const float di = dinv[node];
    const float dii = di * di;

    float4 b = bias4[lane];
    ushort4 h = H4[(size_t)node * 32 + lane];
    float ax = b.x + dii * bf2f(h.x);
    float ay = b.y + dii * bf2f(h.y);
    float az = b.z + dii * bf2f(h.z);
    float aw = b.w + dii * bf2f(h.w);

    int j = 0;
    for (; j + 4 <= m; j += 4) {
        const int base = start + j;
        int2 e0 = erec[base + 0], e1 = erec[base + 1];
        int2 e2 = erec[base + 2], e3 = erec[base + 3];
        float w0 = __int_as_float(e0.y), w1 = __int_as_float(e1.y);
        float w2 = __int_as_float(e2.y), w3 = __int_as_float(e3.y);
        ushort4 v0 = H4[(size_t)e0.x * 32 + lane];
        ushort4 v1 = H4[(size_t)e1.x * 32 + lane];
        ushort4 v2 = H4[(size_t)e2.x * 32 + lane];
        ushort4 v3 = H4[(size_t)e3.x * 32 + lane];
        ax += w0 * bf2f(v0.x); ay += w0 * bf2f(v0.y); az += w0 * bf2f(v0.z); aw += w0 * bf2f(v0.w);
        ax += w1 * bf2f(v1.x); ay += w1 * bf2f(v1.y); az += w1 * bf2f(v1.z); aw += w1 * bf2f(v1.w);
        ax += w2 * bf2f(v2.x); ay += w2 * bf2f(v2.y); az += w2 * bf2f(v2.z); aw += w2 * bf2f(v2.w);
        ax += w3 * bf2f(v3.x); ay += w3 * bf2f(v3.y); az += w3 * bf2f(v3.z); aw += w3 * bf2f(v3.w);
    }
    for (; j < m; ++j) {
        int2 er = erec[start + j];
        float w = __int_as_float(er.y);
        ushort4 v = H4[(size_t)er.x * 32 + lane];
        ax += w * bf2f(v.x); ay += w * bf2f(v.y); az += w * bf2f(v.z); aw += w * bf2f(v.w);
    }
    if (OUT_BF16) {
        ushort4 o;
        o.x = f2bf(fmaxf(ax, 0.f)); o.y = f2bf(fmaxf(ay, 0.f));
        o.z = f2bf(fmaxf(az, 0.f)); o.w = f2bf(fmaxf(aw, 0.f));
        ((ushort4*)OUTv)[(size_t)node * 32 + lane] = o;
    } else {
        float4 o; o.x = ax; o.y = ay; o.z = az; o.w = aw;
        ((float4*)OUTv)[(size_t)node * 32 + lane] = o;
    }
}

extern "C" void kernel_launch(void* const* d_in, const int* in_sizes, int n_in,
                              void* d_out, int out_size, void* d_ws, size_t ws_size,
                              hipStream_t stream) {
    const float* x  = (const float*)d_in[0];
    const int*   ei = (const int*)d_in[1];    // [2,E] int32
    const float* ew = (const float*)d_in[2];
    const float* W1 = (const float*)d_in[3];
    const float* b1 = (const float*)d_in[4];
    const float* W2 = (const float*)d_in[5];
    const float* b2 = (const float*)d_in[6];
    float* out = (float*)d_out;

    const int N = in_sizes[0] / D;
    const int E = in_sizes[2];

    const int C  = (N + CSZ - 1) / CSZ;       // 391 clusters
    const int B1n = (E + EPB - 1) / EPB;      // 147 hist/scat blocks
    const int total = C * B1n;                // 57477 scan elements
    const int sb = (total + 255) / 256;       // 225 (<=256 for scanB2)

    char* p = (char*)d_ws;
    auto alloc = [&](size_t bytes) {
        void* r = (void*)p;
        p += (bytes + 255) & ~(size_t)255;
        return r;
    };
    unsigned int* bh = (unsigned int*)alloc((size_t)total * 4);
    int*   ebase    = (int*)alloc((size_t)total * 4);
    int*   bsums    = (int*)alloc(1024 * 4);
    float* dinv     = (float*)alloc((size_t)N * 4);
    int*   cnt      = (int*)alloc((size_t)N * 4);
    int*   rowstart = (int*)alloc((size_t)N * 4);
    int2*  brec     = (int2*)alloc((size_t)E * 8);
    int2*  erec     = (int2*)alloc((size_t)E * 8);
    unsigned short* Hbuf = (unsigned short*)alloc((size_t)N * D * 2);  // H bf16
    unsigned short* Abuf = (unsigned short*)alloc((size_t)N * D * 2);  // relu(agg1) bf16
    unsigned short* Wt1  = (unsigned short*)alloc(128 * 128 * 2);
    unsigned short* Wt2  = (unsigned short*)alloc(128 * 128 * 2);

    const int gb = (N + 63) / 64;
    const int hb = (N + 7) / 8;

    // 1. W transposes
    k_prep<<<2, 256, 0, stream>>>(W1, Wt1, W2, Wt2);
    // 2. fused: mfma layer-1 || cluster histogram (LDS atomics only)
    k_histmfma<<<gb + B1n, 256, 0, stream>>>(x, Wt1, Hbuf, N, gb, ei, bh, E, C);
    // 3-4. hierarchical exclusive scan (cluster-major)
    k_scanA2<<<sb, 256, 0, stream>>>(bh, ebase, bsums, total, C, B1n);
    k_scanB2<<<sb, 256, 0, stream>>>(ebase, bsums, total);
    // 5. bucket edges by cluster
    k_scat<<<B1n, 256, 0, stream>>>(ei, ew, ebase, brec, E, C, B1n);
    // 6. per-cluster CSR finalize (rowstart/cnt/dinv + ordered records)
    k_cbuild<<<C, 256, 0, stream>>>(brec, ebase, erec, rowstart, cnt, dinv, N, C, B1n, E);
    // 7. edge norm transform
    k_nrm<<<(E + 511) / 512, 256, 0, stream>>>(erec, dinv, E);
    // 8. gather layer-1 -> relu -> bf16
    k_gather<true><<<hb, 256, 0, stream>>>((const ushort4*)Hbuf, erec, rowstart, cnt,
                                           dinv, (const float4*)b1, (void*)Abuf, N);
    // 9. mfma layer-2
    k_mfma2<<<gb, 256, 0, stream>>>(Abuf, Wt2, Hbuf, N);
    // 10. gather layer-2 -> f32 out
    k_gather<false><<<hb, 256, 0, stream>>>((const ushort4*)Hbuf, erec, rowstart, cnt,
                                            dinv, (const float4*)b2, (void*)out, N);
}